// Round 4
// baseline (465.941 us; speedup 1.0000x reference)
//
#include <hip/hip_runtime.h>
#include <math.h>

#define N_NODES 90
#define KSEL 45
#define DIM 1024
#define BATCH 512

// ---------------------------------------------------------------------------
// Kernel A: per-(b,n) row scores. ONE WAVE PER ROW (4 rows / 256-thr block).
// Each lane loads 4 float4 from x_sc, 4 from x_fc, 4 from pool_w (L1-hot)
// -> 12 independent loads in flight before any dependent math (latency fix).
// Reduction is a pure wave-64 butterfly: no LDS, no __syncthreads.
// ---------------------------------------------------------------------------
__global__ __launch_bounds__(256) void score_kernel(
    const float* __restrict__ x_sc, const float* __restrict__ x_fc,
    const float* __restrict__ pool_w, const float* __restrict__ multi_w,
    const float* __restrict__ multi_b, float* __restrict__ scores)
{
    const int wave = threadIdx.x >> 6;
    const int lane = threadIdx.x & 63;
    const int row  = (blockIdx.x << 2) + wave;     // b*N_NODES + n
    const size_t base = (size_t)row * DIM;

    const float4* a4 = (const float4*)(x_sc + base);
    const float4* b4 = (const float4*)(x_fc + base);
    const float4* w4 = (const float4*)pool_w;

    // 12 independent loads — let the compiler issue them all before use.
    float4 a0 = a4[lane];       float4 a1 = a4[lane + 64];
    float4 a2 = a4[lane + 128]; float4 a3 = a4[lane + 192];
    float4 b0 = b4[lane];       float4 b1 = b4[lane + 64];
    float4 b2 = b4[lane + 128]; float4 b3 = b4[lane + 192];
    float4 w0 = w4[lane];       float4 w1 = w4[lane + 64];
    float4 w2 = w4[lane + 128]; float4 w3 = w4[lane + 192];

    float dsc = a0.x*w0.x + a0.y*w0.y + a0.z*w0.z + a0.w*w0.w
              + a1.x*w1.x + a1.y*w1.y + a1.z*w1.z + a1.w*w1.w
              + a2.x*w2.x + a2.y*w2.y + a2.z*w2.z + a2.w*w2.w
              + a3.x*w3.x + a3.y*w3.y + a3.z*w3.z + a3.w*w3.w;
    float dfc = b0.x*w0.x + b0.y*w0.y + b0.z*w0.z + b0.w*w0.w
              + b1.x*w1.x + b1.y*w1.y + b1.z*w1.z + b1.w*w1.w
              + b2.x*w2.x + b2.y*w2.y + b2.z*w2.z + b2.w*w2.w
              + b3.x*w3.x + b3.y*w3.y + b3.z*w3.z + b3.w*w3.w;
    float wsq = w0.x*w0.x + w0.y*w0.y + w0.z*w0.z + w0.w*w0.w
              + w1.x*w1.x + w1.y*w1.y + w1.z*w1.z + w1.w*w1.w
              + w2.x*w2.x + w2.y*w2.y + w2.z*w2.z + w2.w*w2.w
              + w3.x*w3.x + w3.y*w3.y + w3.z*w3.z + w3.w*w3.w;

    // wave-64 butterfly reduction, 3 values, no barriers
    #pragma unroll
    for (int off = 32; off > 0; off >>= 1) {
        dsc += __shfl_down(dsc, off, 64);
        dfc += __shfl_down(dfc, off, 64);
        wsq += __shfl_down(wsq, off, 64);
    }

    if (lane == 0) {
        float inv_norm = rsqrtf(wsq);
        float sc = tanhf(dsc * inv_norm);
        float fc = tanhf(dfc * inv_norm);
        int n = row % N_NODES;
        float z = sc * multi_w[0] + fc * multi_w[1] + multi_b[n];
        scores[row] = 1.0f / (1.0f + expf(-z));
    }
}

// ---------------------------------------------------------------------------
// Kernel B: stable top-K per batch, reproducing argsort(-score) semantics.
// rank(n) = #{j : s[j] > s[n]} + #{j < n : s[j] == s[n]}  (stable tie order)
// ---------------------------------------------------------------------------
__global__ __launch_bounds__(128) void topk_kernel(
    const float* __restrict__ scores, int* __restrict__ idx,
    float* __restrict__ wgt)
{
    const int b = blockIdx.x;
    const int t = threadIdx.x;
    __shared__ float s[N_NODES];
    if (t < N_NODES) s[t] = scores[b * N_NODES + t];
    __syncthreads();
    if (t < N_NODES) {
        float v = s[t];
        int rank = 0;
        #pragma unroll
        for (int j = 0; j < N_NODES; ++j) {
            float u = s[j];
            rank += (u > v) || (u == v && j < t);
        }
        if (rank < KSEL) {
            idx[b * KSEL + rank] = t;
            wgt[b * KSEL + rank] = v;
        }
    }
}

// ---------------------------------------------------------------------------
// Kernel C: gather+scale. ONE WAVE PER OUTPUT ROW (4 rows / 256-thr block).
// Each lane: 4 float4 loads from each tensor (8 in flight) + 8 stores.
// ---------------------------------------------------------------------------
__global__ __launch_bounds__(256) void gather_kernel(
    const float* __restrict__ x_sc, const float* __restrict__ x_fc,
    const int* __restrict__ idx, const float* __restrict__ wgt,
    float* __restrict__ out)
{
    const int wave = threadIdx.x >> 6;
    const int lane = threadIdx.x & 63;
    const int m = (blockIdx.x << 2) + wave;        // b*KSEL + k
    const int b = m / KSEL;

    const int n = idx[m];          // wave-uniform broadcast load
    const float w = wgt[m];

    const size_t src = ((size_t)b * N_NODES + n) * DIM;
    const size_t dst = (size_t)m * DIM;

    const float4* a4 = (const float4*)(x_sc + src);
    const float4* c4 = (const float4*)(x_fc + src);
    float4* o1 = (float4*)(out + dst);
    float4* o2 = (float4*)(out + (size_t)BATCH * KSEL * DIM + dst);

    float4 a0 = a4[lane];       float4 a1 = a4[lane + 64];
    float4 a2 = a4[lane + 128]; float4 a3 = a4[lane + 192];
    float4 c0 = c4[lane];       float4 c1 = c4[lane + 64];
    float4 c2 = c4[lane + 128]; float4 c3 = c4[lane + 192];

    a0.x *= w; a0.y *= w; a0.z *= w; a0.w *= w;
    a1.x *= w; a1.y *= w; a1.z *= w; a1.w *= w;
    a2.x *= w; a2.y *= w; a2.z *= w; a2.w *= w;
    a3.x *= w; a3.y *= w; a3.z *= w; a3.w *= w;
    c0.x *= w; c0.y *= w; c0.z *= w; c0.w *= w;
    c1.x *= w; c1.y *= w; c1.z *= w; c1.w *= w;
    c2.x *= w; c2.y *= w; c2.z *= w; c2.w *= w;
    c3.x *= w; c3.y *= w; c3.z *= w; c3.w *= w;

    o1[lane]       = a0;  o1[lane + 64]  = a1;
    o1[lane + 128] = a2;  o1[lane + 192] = a3;
    o2[lane]       = c0;  o2[lane + 64]  = c1;
    o2[lane + 128] = c2;  o2[lane + 192] = c3;
}

extern "C" void kernel_launch(void* const* d_in, const int* in_sizes, int n_in,
                              void* d_out, int out_size, void* d_ws, size_t ws_size,
                              hipStream_t stream) {
    const float* x_sc    = (const float*)d_in[0];
    const float* x_fc    = (const float*)d_in[1];
    const float* pool_w  = (const float*)d_in[2];
    const float* multi_w = (const float*)d_in[3];
    const float* multi_b = (const float*)d_in[4];
    float* out = (float*)d_out;

    // workspace layout: scores[B*N] | wgt[B*K] | idx[B*K]  (< 400 KB)
    float* scores = (float*)d_ws;
    float* wgt    = scores + BATCH * N_NODES;
    int*   idx    = (int*)(wgt + BATCH * KSEL);

    score_kernel<<<(BATCH * N_NODES) / 4, 256, 0, stream>>>(
        x_sc, x_fc, pool_w, multi_w, multi_b, scores);
    topk_kernel<<<BATCH, 128, 0, stream>>>(scores, idx, wgt);
    gather_kernel<<<(BATCH * KSEL) / 4, 256, 0, stream>>>(
        x_sc, x_fc, idx, wgt, out);
}